// Round 1
// 401.061 us; speedup vs baseline: 1.3015x; 1.3015x over previous
//
#include <hip/hip_runtime.h>
#include <hip/hip_bf16.h>

#define N_ROI 262144
#define FDIM  256
#define HDIM  64
#define NNET  128

#define TILE   128                 // ROIs per tile
#define TILES  8                   // tiles per block
#define RPB    (TILE * TILES)      // 1024 ROIs per block
#define NBLK   (N_ROI / RPB)       // 256 blocks == 1 per CU
#define XPITCH 264                 // shorts; 528 B row stride -> 2-way banks (free)

typedef __attribute__((ext_vector_type(8))) __bf16 bf16x8;
typedef __attribute__((ext_vector_type(8))) short short8;
typedef __attribute__((ext_vector_type(4))) float floatx4;

union frag_cast { short8 s; bf16x8 b; };

#define NEG_INF (-__builtin_huge_valf())

// monotonic float -> uint key (order-preserving), for atomicMax segment max
__device__ __forceinline__ unsigned fkey(float f) {
  unsigned u = __float_as_uint(f);
  return (u & 0x80000000u) ? ~u : (u | 0x80000000u);
}
__device__ __forceinline__ float fkey_inv(unsigned k) {
  unsigned u = (k & 0x80000000u) ? (k ^ 0x80000000u) : ~k;
  return __uint_as_float(u);
}
__device__ __forceinline__ unsigned short f2bf(float f) {  // RNE f32->bf16
  unsigned u = __float_as_uint(f);
  u += 0x7FFFu + ((u >> 16) & 1u);
  return (unsigned short)(u >> 16);
}
__device__ __forceinline__ float bf2f(unsigned short h) {
  return __uint_as_float(((unsigned)h) << 16);
}
// hardware packed cvt (v_cvt_pk_bf16_f32), RNE — hot staging path
__device__ __forceinline__ unsigned cvt2(float a, float b) {
  union { __hip_bfloat162 h; unsigned u; } cv;
  cv.h = __float22bfloat162_rn(make_float2(a, b));
  return cv.u;
}

// ---------------- Fused kernel: scores + online-softmax + scatter-GEMM -----
// One persistent block per CU. Per 128-ROI tile:
//   stage x (bf16, LDS) -> score MFMA (x @ W1, relu, dot W2)
//   -> per-group tile max -> rescale register acc by exp(m_old-m_new)
//   -> w = exp(s - m_new), masked scatter MFMA  num[g][d] += w * x
// Block emits private (num_b[128][256], den_b[128], m_b[128]) — no atomics.
__global__ __launch_bounds__(512, 2) void fused_kernel(
    const float* __restrict__ x, const int* __restrict__ group,
    const float* __restrict__ W1, const float* __restrict__ b1,
    const float* __restrict__ W2,
    float* __restrict__ num_ws,   // [NBLK][128][257]  (d=256 -> denom)
    float* __restrict__ m_ws)     // [NBLK][128]
{
  __shared__ __align__(16) unsigned short w1t[HDIM][XPITCH];  // W1^T bf16
  __shared__ __align__(16) unsigned short xl[TILE][XPITCH];   // x tile bf16
  __shared__ float sc[TILE];
  __shared__ int   ggrp[TILE];
  __shared__ unsigned gw[TILE];       // (g<<16) | bf16(w)
  __shared__ unsigned tmax[NNET];
  __shared__ __align__(16) float fl[NNET];   // per-tile rescale factor
  __shared__ float mrun[NNET];
  __shared__ float dent[NNET];
  __shared__ float denrun[NNET];

  const int tid  = threadIdx.x;
  const int wave = tid >> 6, lane = tid & 63;
  const int col  = lane & 15, quad = lane >> 4;

  // stage W1^T bf16 once (cold)
  {
    const int n = tid & 63, kg = tid >> 6;          // kg 0..7
    for (int p = 0; p < 4; ++p) {
      const int k0 = p * 64 + kg * 8;
      unsigned short tmp[8];
#pragma unroll
      for (int j = 0; j < 8; ++j) tmp[j] = f2bf(W1[(k0 + j) * HDIM + n]);
      *(short8*)&w1t[n][k0] = *(short8*)tmp;
    }
  }
  if (tid < NNET) { mrun[tid] = NEG_INF; denrun[tid] = 0.f; }

  float b1v[4], w2v[4];
#pragma unroll
  for (int nt = 0; nt < 4; ++nt) { b1v[nt] = b1[nt * 16 + col]; w2v[nt] = W2[nt * 16 + col]; }

  floatx4 acc[8][2];        // scatter acc: 128 groups x 32 dims (this wave)
#pragma unroll
  for (int mt = 0; mt < 8; ++mt) { acc[mt][0] = (floatx4)0.f; acc[mt][1] = (floatx4)0.f; }

  const size_t rbase = (size_t)blockIdx.x * RPB;
  const float* xb = x + rbase * FDIM;

  // full-tile register prefetch: 16 float4 / thread = 128 KB / block-tile
  float4 pf[16];
#pragma unroll
  for (int i = 0; i < 16; ++i)
    pf[i] = *(const float4*)(xb + i * 2048 + tid * 4);

  for (int t = 0; t < TILES; ++t) {
    __syncthreads();                 // prev tile's scatter reads of xl done
    // ---- stage x tile (rows i*8+(tid>>6), dims (tid&63)*4 .. +3)
#pragma unroll
    for (int i = 0; i < 16; ++i) {
      const int row = i * 8 + (tid >> 6);
      const int dim = (tid & 63) * 4;
      unsigned lo = cvt2(pf[i].x, pf[i].y);
      unsigned hi = cvt2(pf[i].z, pf[i].w);
      uint2 pk; pk.x = lo; pk.y = hi;
      *(uint2*)&xl[row][dim] = pk;
    }
    if (tid < TILE) {
      ggrp[tid] = group[rbase + t * TILE + tid];
      tmax[tid] = 0u;
      dent[tid] = 0.f;
    }
    __syncthreads();                 // xl / ggrp / tmax / dent ready

    if (t < TILES - 1) {             // issue next tile's loads; land under compute
      const float* xn = xb + (size_t)(t + 1) * TILE * FDIM;
#pragma unroll
      for (int i = 0; i < 16; ++i)
        pf[i] = *(const float4*)(xn + i * 2048 + tid * 4);
    }

    // ---- score phase: wave owns rows [16*wave, 16*wave+16)
    floatx4 accS[4];
#pragma unroll
    for (int nt = 0; nt < 4; ++nt) accS[nt] = (floatx4)0.f;
#pragma unroll
    for (int c = 0; c < 8; ++c) {
      frag_cast af;
      af.s = *(const short8*)&xl[wave * 16 + col][c * 32 + quad * 8];
#pragma unroll
      for (int nt = 0; nt < 4; ++nt) {
        frag_cast bf;
        bf.s = *(const short8*)&w1t[nt * 16 + col][c * 32 + quad * 8];
        accS[nt] = __builtin_amdgcn_mfma_f32_16x16x32_bf16(af.b, bf.b, accS[nt], 0, 0, 0);
      }
    }
    {   // +b1, relu, dot W2, reduce over the 16 cols (b2 cancels in softmax)
      float pr[4];
#pragma unroll
      for (int r = 0; r < 4; ++r) pr[r] = 0.f;
#pragma unroll
      for (int nt = 0; nt < 4; ++nt)
#pragma unroll
        for (int r = 0; r < 4; ++r)
          pr[r] += fmaxf(accS[nt][r] + b1v[nt], 0.f) * w2v[nt];
#pragma unroll
      for (int off = 1; off < 16; off <<= 1)
#pragma unroll
        for (int r = 0; r < 4; ++r) pr[r] += __shfl_xor(pr[r], off, 16);
      if (col == 0) {
#pragma unroll
        for (int r = 0; r < 4; ++r) sc[wave * 16 + quad * 4 + r] = pr[r];
      }
    }
    __syncthreads();                 // sc ready

    if (tid < TILE) atomicMax(&tmax[ggrp[tid]], fkey(sc[tid]));
    __syncthreads();                 // tmax ready
    if (tid < NNET) {                // online max update per group
      const unsigned tk = tmax[tid];
      float f = 1.f;
      if (tk) {
        const float mo = mrun[tid];
        const float mn = fmaxf(mo, fkey_inv(tk));
        f = __expf(mo - mn);         // mo == -inf -> 0
        mrun[tid] = mn;
      }
      fl[tid] = f;
    }
    __syncthreads();                 // fl / mrun ready
    if (tid < TILE) {
      const int g = ggrp[tid];
      const float w = __expf(sc[tid] - mrun[g]);   // w in (0, 1]
      const unsigned short wb = f2bf(w);
      gw[tid] = ((unsigned)ggrp[tid] << 16) | wb;
      atomicAdd(&dent[g], bf2f(wb)); // denom uses the SAME rounded weights as num
    }
    // rescale register accumulators (rows = groups); fl is 16B-aligned reads
#pragma unroll
    for (int mt = 0; mt < 8; ++mt) {
      const floatx4 f4 = *(const floatx4*)&fl[mt * 16 + quad * 4];
#pragma unroll
      for (int r = 0; r < 4; ++r) {
        acc[mt][0][r] *= f4[r];
        acc[mt][1][r] *= f4[r];
      }
    }
    __syncthreads();                 // gw / dent ready
    if (tid < NNET) denrun[tid] = denrun[tid] * fl[tid] + dent[tid];

    // ---- scatter phase: wave owns dims [32*wave, 32*wave+32)
    const int ntb = wave * 32;
#pragma unroll
    for (int c = 0; c < 4; ++c) {    // 4 K-chunks of 32 ROIs
      unsigned gwv[8];
#pragma unroll
      for (int j = 0; j < 8; ++j) gwv[j] = gw[c * 32 + quad * 8 + j];
      frag_cast bfx[2];
#pragma unroll
      for (int nt = 0; nt < 2; ++nt) {
        unsigned short bb[8];
#pragma unroll
        for (int j = 0; j < 8; ++j)
          bb[j] = xl[c * 32 + quad * 8 + j][ntb + nt * 16 + col];
        bfx[nt].s = *(short8*)bb;
      }
#pragma unroll
      for (int mt = 0; mt < 8; ++mt) {
        const unsigned gt = (unsigned)(mt * 16 + col);
        unsigned short aa[8];
#pragma unroll
        for (int j = 0; j < 8; ++j)
          aa[j] = ((gwv[j] >> 16) == gt) ? (unsigned short)gwv[j] : (unsigned short)0;
        frag_cast af; af.s = *(short8*)aa;
        acc[mt][0] = __builtin_amdgcn_mfma_f32_16x16x32_bf16(af.b, bfx[0].b, acc[mt][0], 0, 0, 0);
        acc[mt][1] = __builtin_amdgcn_mfma_f32_16x16x32_bf16(af.b, bfx[1].b, acc[mt][1], 0, 0, 0);
      }
    }
  }

  // ---- store per-block partials (plain stores, private slice, no atomics)
  float* slice = num_ws + (size_t)blockIdx.x * (NNET * 257);
#pragma unroll
  for (int mt = 0; mt < 8; ++mt)
#pragma unroll
    for (int nt = 0; nt < 2; ++nt)
#pragma unroll
      for (int r = 0; r < 4; ++r)
        slice[(mt * 16 + quad * 4 + r) * 257 + wave * 32 + nt * 16 + col] = acc[mt][nt][r];
  if (tid < NNET) {
    slice[tid * 257 + 256] = denrun[tid];
    m_ws[(size_t)blockIdx.x * NNET + tid] = mrun[tid];
  }
}

// ---------------- Finalize: global max per group + rescaled reduction ------
__global__ __launch_bounds__(256) void finalize_kernel(
    const float* __restrict__ num_ws, const float* __restrict__ m_ws,
    float* __restrict__ out)
{
  const int g = blockIdx.x;          // 128
  const int tid = threadIdx.x;       // 256: b index for phase 1, d for phase 2
  __shared__ float e_l[NBLK];
  __shared__ float dsum[NBLK];
  __shared__ float wm[4];

  const float mb = m_ws[(size_t)tid * NNET + g];
  float M = mb;
#pragma unroll
  for (int off = 1; off < 64; off <<= 1) M = fmaxf(M, __shfl_xor(M, off));
  if ((tid & 63) == 0) wm[tid >> 6] = M;
  __syncthreads();
  M = fmaxf(fmaxf(wm[0], wm[1]), fmaxf(wm[2], wm[3]));

  const float eb = (mb == NEG_INF) ? 0.f : __expf(mb - M);
  const float db = num_ws[(size_t)tid * (NNET * 257) + g * 257 + 256];
  e_l[tid]  = eb;
  dsum[tid] = db * eb;
  __syncthreads();

  float num = 0.f, den = 0.f;
#pragma unroll 4
  for (int b = 0; b < NBLK; ++b) {
    num += num_ws[(size_t)b * (NNET * 257) + g * 257 + tid] * e_l[b];  // coalesced in tid
    den += dsum[b];
  }
  out[g * FDIM + tid] = (den > 0.f) ? num / fmaxf(den, 1e-30f) : 0.f;
}

extern "C" void kernel_launch(void* const* d_in, const int* in_sizes, int n_in,
                              void* d_out, int out_size, void* d_ws, size_t ws_size,
                              hipStream_t stream)
{
  const float* x     = (const float*)d_in[0];
  const int*   group = (const int*)d_in[1];
  const float* W1    = (const float*)d_in[2];
  const float* b1    = (const float*)d_in[3];
  const float* W2    = (const float*)d_in[4];
  // d_in[5] = b2: cancels exactly in exp(score-max)/sum -> unused
  float* out = (float*)d_out;

  // workspace: num[NBLK][128][257] | m[NBLK][128]  — fully overwritten, no memset
  float* num_ws = (float*)d_ws;
  float* m_ws   = num_ws + (size_t)NBLK * NNET * 257;

  fused_kernel<<<NBLK, 512, 0, stream>>>(x, group, W1, b1, W2, num_ws, m_ws);
  finalize_kernel<<<NNET, 256, 0, stream>>>(num_ws, m_ws, out);

  (void)in_sizes; (void)n_in; (void)out_size; (void)ws_size;
}